// Round 3
// baseline (123.809 us; speedup 1.0000x reference)
//
#include <hip/hip_runtime.h>
#include <stdint.h>

// Problem dims (fixed by reference)
#define BB   8
#define SS   2048
#define DIN  1024
#define DOUT 64

typedef __bf16 bf16_t;
typedef __bf16 bf16x8 __attribute__((ext_vector_type(8)));
typedef float  f32x4  __attribute__((ext_vector_type(4)));
typedef unsigned int u32x4 __attribute__((ext_vector_type(4)));
typedef unsigned short us8 __attribute__((ext_vector_type(8)));

#define LOG2E 1.44269504088896f

// ---------------------------------------------------------------------------
// Kernel 0: pre-pack weights (1024x64 fp32) into bf16 MFMA B-fragment order.
// Layout: fw[proj][kk=0..31][nt=0..3][lane=0..63][j=0..7]
//   value = W[k][col],  k = kk*32 + (lane>>4)*8 + j,  col = nt*16 + (lane&15)
// Q weights (proj==2) scaled by 1/sqrt(64) = 0.125 (exact).
// ---------------------------------------------------------------------------
__global__ void prep_weights(const float* __restrict__ Kw,
                             const float* __restrict__ Vw,
                             const float* __restrict__ Qw,
                             bf16_t* __restrict__ fw) {
    int proj = blockIdx.x >> 4;
    int seg  = blockIdx.x & 15;
    const float* W = (proj == 0) ? Kw : (proj == 1) ? Vw : Qw;
    float scale = (proj == 2) ? 0.125f : 1.0f;
    bf16_t* out = fw + proj * 65536;
    int base = seg * 4096;
#pragma unroll
    for (int i = 0; i < 16; ++i) {
        int idx  = base + i * 256 + threadIdx.x;
        int j    = idx & 7;
        int lane = (idx >> 3) & 63;
        int nt   = (idx >> 9) & 3;
        int kk   = idx >> 11;
        int k    = kk * 32 + (lane >> 4) * 8 + j;
        int col  = nt * 16 + (lane & 15);
        out[idx] = (bf16_t)(W[k * DOUT + col] * scale);
    }
}

// ---------------------------------------------------------------------------
// Kernel 1: projection GEMM  [16384,1024](fp32) x [1024,64](bf16) -> bf16
// Block: 256 thr = 4 waves, 64 rows. B staged in LDS one 64KB K-half at a
// time (acc carries across halves -> no reduction). A loads from global with
// explicit 2-pair register prefetch (4 f32x4 in flight, all static indices).
// LDS 64KB -> 2 blocks/CU; launch_bounds(256,2) -> VGPR cap 256 (no
// compiler occupancy-starvation of registers like round 2's 32-VGPR alloc).
// ---------------------------------------------------------------------------
__global__ __launch_bounds__(256, 2) void proj_kernel(
    const float* __restrict__ Xk, const float* __restrict__ Xv,
    const float* __restrict__ Xq, const bf16_t* __restrict__ fw,
    bf16_t* __restrict__ outK, bf16_t* __restrict__ outV,
    bf16_t* __restrict__ outQ) {
    __shared__ __align__(16) bf16_t Blds[32768];   // 64 KB: one K-half of B

    int tid  = threadIdx.x;
    int lane = tid & 63;
    int w    = tid >> 6;    // 0..3

    int proj = blockIdx.y;
    const float* X  = (proj == 0) ? Xk : (proj == 1) ? Xv : Xq;
    bf16_t* out     = (proj == 0) ? outK : (proj == 1) ? outV : outQ;
    const bf16_t* fwp = fw + proj * 65536;

    int row0 = blockIdx.x * 64 + w * 16;
    const float* aptr = X + (size_t)(row0 + (lane & 15)) * DIN + (lane >> 4) * 8;

    f32x4 acc[4];
#pragma unroll
    for (int nt = 0; nt < 4; ++nt) acc[nt] = (f32x4)(0.0f);

    for (int kh = 0; kh < 2; ++kh) {
        __syncthreads();   // protect LDS overwrite (trivial first pass)
        {
            const u32x4* src = (const u32x4*)(fwp + kh * 32768);
            u32x4* dst = (u32x4*)Blds;
#pragma unroll
            for (int i = 0; i < 16; ++i) dst[tid + 256 * i] = src[tid + 256 * i];
        }
        __syncthreads();

        const float* ah = aptr + kh * 512;
        // prologue: prefetch kk=0,1
        f32x4 a00 = *(const f32x4*)(ah);
        f32x4 a01 = *(const f32x4*)(ah + 4);
        f32x4 a10 = *(const f32x4*)(ah + 32);
        f32x4 a11 = *(const f32x4*)(ah + 36);

#pragma unroll
        for (int kk = 0; kk < 16; kk += 2) {
            f32x4 n00, n01, n10, n11;
            if (kk < 14) {
                n00 = *(const f32x4*)(ah + (kk + 2) * 32);
                n01 = *(const f32x4*)(ah + (kk + 2) * 32 + 4);
                n10 = *(const f32x4*)(ah + (kk + 3) * 32);
                n11 = *(const f32x4*)(ah + (kk + 3) * 32 + 4);
            }
            bf16x8 af0;
            af0[0] = (bf16_t)a00[0]; af0[1] = (bf16_t)a00[1];
            af0[2] = (bf16_t)a00[2]; af0[3] = (bf16_t)a00[3];
            af0[4] = (bf16_t)a01[0]; af0[5] = (bf16_t)a01[1];
            af0[6] = (bf16_t)a01[2]; af0[7] = (bf16_t)a01[3];
#pragma unroll
            for (int nt = 0; nt < 4; ++nt) {
                bf16x8 b = *(const bf16x8*)(Blds + ((kk * 4 + nt) * 512 + lane * 8));
                acc[nt] = __builtin_amdgcn_mfma_f32_16x16x32_bf16(af0, b, acc[nt], 0, 0, 0);
            }
            bf16x8 af1;
            af1[0] = (bf16_t)a10[0]; af1[1] = (bf16_t)a10[1];
            af1[2] = (bf16_t)a10[2]; af1[3] = (bf16_t)a10[3];
            af1[4] = (bf16_t)a11[0]; af1[5] = (bf16_t)a11[1];
            af1[6] = (bf16_t)a11[2]; af1[7] = (bf16_t)a11[3];
#pragma unroll
            for (int nt = 0; nt < 4; ++nt) {
                bf16x8 b = *(const bf16x8*)(Blds + (((kk + 1) * 4 + nt) * 512 + lane * 8));
                acc[nt] = __builtin_amdgcn_mfma_f32_16x16x32_bf16(af1, b, acc[nt], 0, 0, 0);
            }
            a00 = n00; a01 = n01; a10 = n10; a11 = n11;
        }
    }

    // write bf16 [row][64]; C/D layout: col = lane&15 (+16*nt), row = (lane>>4)*4 + r
#pragma unroll
    for (int nt = 0; nt < 4; ++nt)
#pragma unroll
        for (int r = 0; r < 4; ++r) {
            int rr = (lane >> 4) * 4 + r;
            int cc = nt * 16 + (lane & 15);
            out[(size_t)(row0 + rr) * DOUT + cc] = (bf16_t)acc[nt][r];
        }
}

// ---------------------------------------------------------------------------
// Kernel 2: causal flash attention, bf16 MFMA, fp32 accum.
// Grid: (64 q-tiles of 32 rows, 8 batches) = 512 blocks; block = 128 thr =
// 2 waves (16 q-rows each). K/V double-buffered in LDS; register prefetch of
// tile t+1 issued before compute of tile t; ds_write after compute; ONE
// barrier per tile. LDS 36KB -> up to 4 blocks/CU; avg grid 2/CU -> the
// causal work imbalance (1..32 tiles/block) backfills across CUs.
// K LDS: [key][d] byte ^= (key&7)<<4;  V LDS: [d][key] byte ^= (d&7)<<4;
// P LDS: per-wave [q][key] byte ^= (q&7)<<4.
// ---------------------------------------------------------------------------
__global__ __launch_bounds__(128, 3) void attn_kernel(
    const bf16_t* __restrict__ Kp, const bf16_t* __restrict__ Vp,
    const bf16_t* __restrict__ Qp, float* __restrict__ out) {
    __shared__ __align__(16) bf16_t Kl[2][64 * 64];   // 2 x 8 KB
    __shared__ __align__(16) bf16_t Vl[2][64 * 64];   // 2 x 8 KB (transposed)
    __shared__ __align__(16) bf16_t Pl[2][16 * 64];   // 2 x 2 KB (per wave)

    int tid   = threadIdx.x;   // 0..127
    int lane  = tid & 63;
    int w     = tid >> 6;      // 0..1
    int qt    = blockIdx.x;    // 0..63
    int batch = blockIdx.y;

    const bf16_t* Kb = Kp + (size_t)batch * SS * DOUT;
    const bf16_t* Vb = Vp + (size_t)batch * SS * DOUT;
    const bf16_t* Qb = Qp + (size_t)batch * SS * DOUT;

    // Q fragments (already scaled by 1/8)
    bf16x8 aq0, aq1;
    {
        int r = qt * 32 + w * 16 + (lane & 15);
        const bf16_t* qp = Qb + (size_t)r * DOUT + (lane >> 4) * 8;
        aq0 = *(const bf16x8*)(qp);
        aq1 = *(const bf16x8*)(qp + 32);
    }

    float m[4], lsum[4];
    f32x4 acc[4];
#pragma unroll
    for (int r = 0; r < 4; ++r) { m[r] = -1e30f; lsum[r] = 0.0f; }
#pragma unroll
    for (int nt = 0; nt < 4; ++nt) acc[nt] = (f32x4)(0.0f);

    int dt  = qt >> 1;     // diagonal 64-key tile
    int ntl = dt + 1;

    // staging chunk indices for this thread:
    // K: chunks tid+128*i, i=0..3: key=ch>>3, d0=(ch&7)*8  (16B each)
    // V: chunks tid+128*i, i=0..1: key0=(vch>>3)*2, d0=(vch&7)*8 (2 keys x 8 d)
    // ---- prologue: stage tile 0 into buffer 0 ----
    {
        const bf16_t* Kt = Kb;
        const bf16_t* Vt = Vb;
#pragma unroll
        for (int i = 0; i < 4; ++i) {
            int ch  = tid + 128 * i;
            int key = ch >> 3;
            int d0  = (ch & 7) * 8;
            u32x4 kv = *(const u32x4*)(Kt + (size_t)key * DOUT + d0);
            *(u32x4*)((char*)&Kl[0][0] + key * 128 + ((d0 * 2) ^ ((key & 7) << 4))) = kv;
        }
#pragma unroll
        for (int i = 0; i < 2; ++i) {
            int vch  = tid + 128 * i;
            int key0 = (vch >> 3) * 2;
            int d0   = (vch & 7) * 8;
            us8 va = *(const us8*)(Vt + (size_t)key0 * DOUT + d0);
            us8 vb = *(const us8*)(Vt + (size_t)(key0 + 1) * DOUT + d0);
#pragma unroll
            for (int jj = 0; jj < 8; ++jj) {
                int d = d0 + jj;
                unsigned int pack = (unsigned int)va[jj] | ((unsigned int)vb[jj] << 16);
                *(unsigned int*)((char*)&Vl[0][0] + d * 128 + ((key0 * 2) ^ ((d & 7) << 4))) = pack;
            }
        }
    }
    __syncthreads();

    for (int t = 0; t < ntl; ++t) {
        int cur = t & 1;
        bool pf = (t + 1) < ntl;

        // ---- issue prefetch loads for tile t+1 (latency hides under compute) ----
        u32x4 pk0, pk1, pk2, pk3;
        us8 pva0, pvb0, pva1, pvb1;
        int vkey0_0 = ((tid) >> 3) * 2,       vd0_0 = (tid & 7) * 8;
        int vkey0_1 = ((tid + 128) >> 3) * 2, vd0_1 = (tid & 7) * 8;
        if (pf) {
            const bf16_t* Kt = Kb + (size_t)(t + 1) * 64 * DOUT;
            const bf16_t* Vt = Vb + (size_t)(t + 1) * 64 * DOUT;
            pk0 = *(const u32x4*)(Kt + (size_t)((tid) >> 3) * DOUT + (tid & 7) * 8);
            pk1 = *(const u32x4*)(Kt + (size_t)((tid + 128) >> 3) * DOUT + (tid & 7) * 8);
            pk2 = *(const u32x4*)(Kt + (size_t)((tid + 256) >> 3) * DOUT + (tid & 7) * 8);
            pk3 = *(const u32x4*)(Kt + (size_t)((tid + 384) >> 3) * DOUT + (tid & 7) * 8);
            pva0 = *(const us8*)(Vt + (size_t)vkey0_0 * DOUT + vd0_0);
            pvb0 = *(const us8*)(Vt + (size_t)(vkey0_0 + 1) * DOUT + vd0_0);
            pva1 = *(const us8*)(Vt + (size_t)vkey0_1 * DOUT + vd0_1);
            pvb1 = *(const us8*)(Vt + (size_t)(vkey0_1 + 1) * DOUT + vd0_1);
        }

        char* Kc = (char*)&Kl[cur][0];
        char* Vc = (char*)&Vl[cur][0];

        // ---- S = Q K^T ----
        f32x4 sfr[4];
#pragma unroll
        for (int nt = 0; nt < 4; ++nt) sfr[nt] = (f32x4)(0.0f);
#pragma unroll
        for (int kk = 0; kk < 2; ++kk) {
            int d0 = kk * 32 + (lane >> 4) * 8;
#pragma unroll
            for (int nt = 0; nt < 4; ++nt) {
                int key = nt * 16 + (lane & 15);
                bf16x8 bk = *(const bf16x8*)(Kc + key * 128 +
                                             ((d0 * 2) ^ ((key & 7) << 4)));
                sfr[nt] = __builtin_amdgcn_mfma_f32_16x16x32_bf16(
                              kk == 0 ? aq0 : aq1, bk, sfr[nt], 0, 0, 0);
            }
        }

        // ---- causal mask (diagonal tile only) ----
        if (t == dt) {
#pragma unroll
            for (int nt = 0; nt < 4; ++nt) {
                int keyg = t * 64 + nt * 16 + (lane & 15);
#pragma unroll
                for (int r = 0; r < 4; ++r) {
                    int qg = qt * 32 + w * 16 + (lane >> 4) * 4 + r;
                    if (keyg > qg) sfr[nt][r] = -1e30f;
                }
            }
        }

        // ---- online softmax (rows live in 16-lane groups) ----
        float pfv[4][4];
#pragma unroll
        for (int r = 0; r < 4; ++r) {
            float mx = fmaxf(fmaxf(sfr[0][r], sfr[1][r]), fmaxf(sfr[2][r], sfr[3][r]));
            mx = fmaxf(mx, __shfl_xor(mx, 1));
            mx = fmaxf(mx, __shfl_xor(mx, 2));
            mx = fmaxf(mx, __shfl_xor(mx, 4));
            mx = fmaxf(mx, __shfl_xor(mx, 8));
            float mn = fmaxf(m[r], mx);
            float scale = exp2f((m[r] - mn) * LOG2E);
            m[r] = mn;
            float rs = 0.0f;
#pragma unroll
            for (int nt = 0; nt < 4; ++nt) {
                float p = exp2f((sfr[nt][r] - mn) * LOG2E);
                pfv[nt][r] = p;
                rs += p;
            }
            rs += __shfl_xor(rs, 1);
            rs += __shfl_xor(rs, 2);
            rs += __shfl_xor(rs, 4);
            rs += __shfl_xor(rs, 8);
            lsum[r] = lsum[r] * scale + rs;
#pragma unroll
            for (int nt = 0; nt < 4; ++nt) acc[nt][r] *= scale;
        }

        // ---- P -> LDS (bf16, swizzled), re-fragment for PV ----
#pragma unroll
        for (int nt = 0; nt < 4; ++nt) {
            int key = nt * 16 + (lane & 15);
#pragma unroll
            for (int r = 0; r < 4; ++r) {
                int q = (lane >> 4) * 4 + r;
                *(bf16_t*)((char*)&Pl[w][0] + q * 128 +
                           ((key * 2) ^ ((q & 7) << 4))) = (bf16_t)pfv[nt][r];
            }
        }

        // ---- O += P V ---- (same-wave LDS dep; compiler inserts lgkmcnt)
#pragma unroll
        for (int kk = 0; kk < 2; ++kk) {
            int k0 = kk * 32 + (lane >> 4) * 8;
            int q  = lane & 15;
            bf16x8 ap = *(const bf16x8*)((char*)&Pl[w][0] + q * 128 +
                                         ((k0 * 2) ^ ((q & 7) << 4)));
#pragma unroll
            for (int nt = 0; nt < 4; ++nt) {
                int d = nt * 16 + (lane & 15);
                bf16x8 bv = *(const bf16x8*)(Vc + d * 128 +
                                             ((k0 * 2) ^ ((d & 7) << 4)));
                acc[nt] = __builtin_amdgcn_mfma_f32_16x16x32_bf16(ap, bv, acc[nt], 0, 0, 0);
            }
        }

        // ---- write prefetched tile t+1 into the other buffer ----
        if (pf) {
            char* Kn = (char*)&Kl[cur ^ 1][0];
            char* Vn = (char*)&Vl[cur ^ 1][0];
            {
                int key = (tid) >> 3, d0 = (tid & 7) * 8;
                *(u32x4*)(Kn + key * 128 + ((d0 * 2) ^ ((key & 7) << 4))) = pk0;
            }
            {
                int key = (tid + 128) >> 3, d0 = (tid & 7) * 8;
                *(u32x4*)(Kn + key * 128 + ((d0 * 2) ^ ((key & 7) << 4))) = pk1;
            }
            {
                int key = (tid + 256) >> 3, d0 = (tid & 7) * 8;
                *(u32x4*)(Kn + key * 128 + ((d0 * 2) ^ ((key & 7) << 4))) = pk2;
            }
            {
                int key = (tid + 384) >> 3, d0 = (tid & 7) * 8;
                *(u32x4*)(Kn + key * 128 + ((d0 * 2) ^ ((key & 7) << 4))) = pk3;
            }
#pragma unroll
            for (int jj = 0; jj < 8; ++jj) {
                int d = vd0_0 + jj;
                unsigned int pack = (unsigned int)pva0[jj] | ((unsigned int)pvb0[jj] << 16);
                *(unsigned int*)(Vn + d * 128 + ((vkey0_0 * 2) ^ ((d & 7) << 4))) = pack;
            }
#pragma unroll
            for (int jj = 0; jj < 8; ++jj) {
                int d = vd0_1 + jj;
                unsigned int pack = (unsigned int)pva1[jj] | ((unsigned int)pvb1[jj] << 16);
                *(unsigned int*)(Vn + d * 128 + ((vkey0_1 * 2) ^ ((d & 7) << 4))) = pack;
            }
        }
        __syncthreads();
    }

    // ---- epilogue: normalize and write fp32 ----
    float* ob = out + ((size_t)batch * SS + qt * 32 + w * 16) * DOUT;
#pragma unroll
    for (int nt = 0; nt < 4; ++nt)
#pragma unroll
        for (int r = 0; r < 4; ++r) {
            int rr = (lane >> 4) * 4 + r;
            int cc = nt * 16 + (lane & 15);
            ob[(size_t)rr * DOUT + cc] = acc[nt][r] / lsum[r];
        }
}

// ---------------------------------------------------------------------------
// Workspace layout (~6.4 MB):
//   [0, 2MB)   Kp bf16 [8][2048][64]
//   [2, 4MB)   Vp bf16
//   [4, 6MB)   Qp bf16 (pre-scaled by 1/8)
//   [6MB, +384KB) fw bf16 [3][65536] fragment-packed weights
// ---------------------------------------------------------------------------
extern "C" void kernel_launch(void* const* d_in, const int* in_sizes, int n_in,
                              void* d_out, int out_size, void* d_ws, size_t ws_size,
                              hipStream_t stream) {
    const float* Xk = (const float*)d_in[0];
    const float* Xv = (const float*)d_in[1];
    const float* Xq = (const float*)d_in[2];
    const float* Kw = (const float*)d_in[3];
    const float* Vw = (const float*)d_in[4];
    const float* Qw = (const float*)d_in[5];

    bf16_t* Kp = (bf16_t*)d_ws;
    bf16_t* Vp = Kp + (size_t)BB * SS * DOUT;
    bf16_t* Qp = Vp + (size_t)BB * SS * DOUT;
    bf16_t* fw = Qp + (size_t)BB * SS * DOUT;

    prep_weights<<<dim3(48), dim3(256), 0, stream>>>(Kw, Vw, Qw, fw);
    proj_kernel<<<dim3(256, 3), dim3(256), 0, stream>>>(Xk, Xv, Xq, fw, Kp, Vp, Qp);
    attn_kernel<<<dim3(64, 8), dim3(128), 0, stream>>>(Kp, Vp, Qp, (float*)d_out);
}

// Round 4
// 117.549 us; speedup vs baseline: 1.0533x; 1.0533x over previous
//
#include <hip/hip_runtime.h>
#include <stdint.h>

// Problem dims (fixed by reference)
#define BB   8
#define SS   2048
#define DIN  1024
#define DOUT 64

typedef __bf16 bf16_t;
typedef __bf16 bf16x4 __attribute__((ext_vector_type(4)));
typedef __bf16 bf16x8 __attribute__((ext_vector_type(8)));
typedef float  f32x4  __attribute__((ext_vector_type(4)));
typedef unsigned int u32x4 __attribute__((ext_vector_type(4)));

#define LOG2E 1.44269504088896f

// ---------------------------------------------------------------------------
// Kernel 0: pre-pack weights (1024x64 fp32) into bf16 MFMA B-fragment order.
// Layout: fw[proj][kk=0..31][nt=0..3][lane=0..63][j=0..7]
//   value = W[k][col],  k = kk*32 + (lane>>4)*8 + j,  col = nt*16 + (lane&15)
// Q weights (proj==2) scaled by 1/sqrt(64) = 0.125 (exact).
// ---------------------------------------------------------------------------
__global__ void prep_weights(const float* __restrict__ Kw,
                             const float* __restrict__ Vw,
                             const float* __restrict__ Qw,
                             bf16_t* __restrict__ fw) {
    int proj = blockIdx.x >> 4;
    int seg  = blockIdx.x & 15;
    const float* W = (proj == 0) ? Kw : (proj == 1) ? Vw : Qw;
    float scale = (proj == 2) ? 0.125f : 1.0f;
    bf16_t* out = fw + proj * 65536;
    int base = seg * 4096;
#pragma unroll
    for (int i = 0; i < 16; ++i) {
        int idx  = base + i * 256 + threadIdx.x;
        int j    = idx & 7;
        int lane = (idx >> 3) & 63;
        int nt   = (idx >> 9) & 3;
        int kk   = idx >> 11;
        int k    = kk * 32 + (lane >> 4) * 8 + j;
        int col  = nt * 16 + (lane & 15);
        out[idx] = (bf16_t)(W[k * DOUT + col] * scale);
    }
}

// ---------------------------------------------------------------------------
// Kernel 1: projection GEMM  [16384,1024](fp32) x [1024,64](bf16) -> bf16
//
// Round-4 structure: the A read is restructured for HBM-channel density.
// Rounds 1-3 all read A as 16 rows x 16B at 4KB stride (only a 128B column
// window varying) -> ~1.3 TB/s channel-aliased ceiling, ~95% stall.
// Now each staging instruction reads ONE FULL 4KB row contiguously
// (256 thr x 16B), converts to bf16, and stores into a 64KB swizzled LDS
// tile (32 rows x 1024, row stride 2048B, byte ^= (row&7)<<4).
// Compute: 4 waves, each owns a K-quarter (256), computes 2 row-tiles x 64
// cols; B-frags stream from packed fw (L2-resident, 1KB contiguous/load).
// Partials reduced through LDS (reusing the A buffer). 2 blocks/CU.
// ---------------------------------------------------------------------------
__global__ __launch_bounds__(256, 2) void proj_kernel(
    const float* __restrict__ Xk, const float* __restrict__ Xv,
    const float* __restrict__ Xq, const bf16_t* __restrict__ fw,
    bf16_t* __restrict__ outK, bf16_t* __restrict__ outV,
    bf16_t* __restrict__ outQ) {
    __shared__ __align__(128) char Alds[65536];   // 32 rows x 2048B (bf16, swizzled)

    int tid  = threadIdx.x;
    int lane = tid & 63;
    int w    = tid >> 6;    // 0..3 (K-quarter)

    int proj = blockIdx.y;
    const float* X  = (proj == 0) ? Xk : (proj == 1) ? Xv : Xq;
    bf16_t* out     = (proj == 0) ? outK : (proj == 1) ? outV : outQ;
    const bf16_t* fwp = fw + proj * 65536;

    int row0 = blockIdx.x * 32;

    // ---- Phase 1: stage 32 full rows of A, contiguous 4KB per instruction ----
#pragma unroll
    for (int j = 0; j < 32; ++j) {
        f32x4 v = *(const f32x4*)(X + (size_t)(row0 + j) * DIN + tid * 4);
        bf16x4 b;
        b[0] = (bf16_t)v[0]; b[1] = (bf16_t)v[1];
        b[2] = (bf16_t)v[2]; b[3] = (bf16_t)v[3];
        *(bf16x4*)(Alds + j * 2048 + ((tid * 8) ^ ((j & 7) << 4))) = b;
    }
    __syncthreads();

    // ---- Phase 2: MFMA over this wave's K-quarter ----
    f32x4 acc[2][4];   // [row-tile 0/1][nt]
#pragma unroll
    for (int t = 0; t < 2; ++t)
#pragma unroll
        for (int nt = 0; nt < 4; ++nt) acc[t][nt] = (f32x4)(0.0f);

    int arow = lane & 15;
#pragma unroll
    for (int kk = 0; kk < 8; ++kk) {
        int k0 = w * 256 + kk * 32;
        int kb = (k0 + (lane >> 4) * 8) * 2;               // byte offset in row
        int sw = kb ^ ((arow & 7) << 4);
        bf16x8 a0 = *(const bf16x8*)(Alds + arow * 2048 + sw);
        bf16x8 a1 = *(const bf16x8*)(Alds + (arow + 16) * 2048 + sw);
        const bf16_t* bp = fwp + (size_t)((k0 >> 5) * 4) * 512 + lane * 8;
#pragma unroll
        for (int nt = 0; nt < 4; ++nt) {
            bf16x8 b = *(const bf16x8*)(bp + nt * 512);
            acc[0][nt] = __builtin_amdgcn_mfma_f32_16x16x32_bf16(a0, b, acc[0][nt], 0, 0, 0);
            acc[1][nt] = __builtin_amdgcn_mfma_f32_16x16x32_bf16(a1, b, acc[1][nt], 0, 0, 0);
        }
    }

    // ---- Phase 3: reduce K-quarters through LDS (reuse A buffer) ----
    __syncthreads();   // all A-frag reads done
    float* red = (float*)Alds;            // [4][32][64] fp32 = 32 KB
#pragma unroll
    for (int t = 0; t < 2; ++t)
#pragma unroll
        for (int nt = 0; nt < 4; ++nt)
#pragma unroll
            for (int r = 0; r < 4; ++r) {
                int row = t * 16 + (lane >> 4) * 4 + r;
                int col = nt * 16 + (lane & 15);
                red[w * 2048 + row * 64 + col] = acc[t][nt][r];
            }
    __syncthreads();
    // each wave reduces+stores rows [w*8, w*8+8)
#pragma unroll
    for (int i = 0; i < 8; ++i) {
        int row = w * 8 + i;
        float s = red[row * 64 + lane] + red[2048 + row * 64 + lane] +
                  red[4096 + row * 64 + lane] + red[6144 + row * 64 + lane];
        out[(size_t)(row0 + row) * DOUT + lane] = (bf16_t)s;
    }
}

// ---------------------------------------------------------------------------
// Kernel 2: causal flash attention (round-1 version: best measured ~25us).
// Grid: (32 q-tiles, 8 batches). Block: 256 thr = 4 waves x 16 q-rows.
// K LDS:  [key][d] with byte ^= (key&7)<<4 swizzle
// V LDS:  transposed [d][key], byte ^= (d&7)<<4
// P LDS:  per-wave [q][key], byte ^= (q&7)<<4
// ---------------------------------------------------------------------------
__global__ __launch_bounds__(256) void attn_kernel(
    const bf16_t* __restrict__ Kp, const bf16_t* __restrict__ Vp,
    const bf16_t* __restrict__ Qp, float* __restrict__ out) {
    __shared__ __align__(16) bf16_t Klds[64 * 64];      // 8 KB
    __shared__ __align__(16) bf16_t Vlds[64 * 64];      // 8 KB (transposed)
    __shared__ __align__(16) bf16_t Plds[4][16 * 64];   // 8 KB

    int tid   = threadIdx.x;
    int lane  = tid & 63;
    int w     = tid >> 6;
    int qtile = blockIdx.x;
    int batch = blockIdx.y;

    const bf16_t* Kb = Kp + (size_t)batch * SS * DOUT;
    const bf16_t* Vb = Vp + (size_t)batch * SS * DOUT;
    const bf16_t* Qb = Qp + (size_t)batch * SS * DOUT;

    // Q fragments (Q already scaled by 1/8): A-frag row = lane&15
    bf16x8 aq[2];
    {
        int r = qtile * 64 + w * 16 + (lane & 15);
        const bf16_t* qp = Qb + (size_t)r * DOUT + (lane >> 4) * 8;
        aq[0] = *(const bf16x8*)(qp);
        aq[1] = *(const bf16x8*)(qp + 32);
    }

    float m[4], lsum[4];
    f32x4 acc[4];
#pragma unroll
    for (int r = 0; r < 4; ++r) { m[r] = -1e30f; lsum[r] = 0.0f; }
#pragma unroll
    for (int nt = 0; nt < 4; ++nt) acc[nt] = (f32x4)(0.0f);

    int ntiles = qtile + 1;
    for (int j = 0; j < ntiles; ++j) {
        __syncthreads();
        // ---- stage K tile (swizzled) and V tile (transposed, swizzled) ----
#pragma unroll
        for (int i = 0; i < 2; ++i) {
            int c   = tid + 256 * i;          // 0..511
            int key = c >> 3;
            int d0  = (c & 7) * 8;
            u32x4 v = *(const u32x4*)(Kb + ((size_t)(j * 64 + key)) * DOUT + d0);
            *(u32x4*)((char*)Klds + key * 128 + ((d0 * 2) ^ ((key & 7) << 4))) = v;
        }
#pragma unroll
        for (int i = 0; i < 2; ++i) {
            int c   = tid + 256 * i;
            int key = c >> 3;
            int d0  = (c & 7) * 8;
            bf16x8 v = *(const bf16x8*)(Vb + ((size_t)(j * 64 + key)) * DOUT + d0);
#pragma unroll
            for (int jj = 0; jj < 8; ++jj) {
                int d = d0 + jj;
                *(bf16_t*)((char*)Vlds + d * 128 + ((key * 2) ^ ((d & 7) << 4))) = v[jj];
            }
        }
        __syncthreads();

        // ---- S = Q K^T (scaled) ----
        f32x4 sfr[4];
#pragma unroll
        for (int nt = 0; nt < 4; ++nt) sfr[nt] = (f32x4)(0.0f);
#pragma unroll
        for (int kk = 0; kk < 2; ++kk) {
            int d0 = kk * 32 + (lane >> 4) * 8;
#pragma unroll
            for (int nt = 0; nt < 4; ++nt) {
                int key = nt * 16 + (lane & 15);
                bf16x8 bk = *(const bf16x8*)((char*)Klds + key * 128 +
                                             ((d0 * 2) ^ ((key & 7) << 4)));
                sfr[nt] = __builtin_amdgcn_mfma_f32_16x16x32_bf16(aq[kk], bk, sfr[nt], 0, 0, 0);
            }
        }

        // ---- causal mask (only diagonal tile) ----
        if (j == qtile) {
#pragma unroll
            for (int nt = 0; nt < 4; ++nt) {
                int key = nt * 16 + (lane & 15);
#pragma unroll
                for (int r = 0; r < 4; ++r) {
                    int q = w * 16 + (lane >> 4) * 4 + r;
                    if (key > q) sfr[nt][r] = -1e30f;
                }
            }
        }

        // ---- online softmax (rows live in 16-lane groups) ----
        float pf[4][4];  // [nt][r]
#pragma unroll
        for (int r = 0; r < 4; ++r) {
            float mx = fmaxf(fmaxf(sfr[0][r], sfr[1][r]), fmaxf(sfr[2][r], sfr[3][r]));
            mx = fmaxf(mx, __shfl_xor(mx, 1));
            mx = fmaxf(mx, __shfl_xor(mx, 2));
            mx = fmaxf(mx, __shfl_xor(mx, 4));
            mx = fmaxf(mx, __shfl_xor(mx, 8));
            float mn = fmaxf(m[r], mx);
            float scale = exp2f((m[r] - mn) * LOG2E);
            m[r] = mn;
            float rs = 0.0f;
#pragma unroll
            for (int nt = 0; nt < 4; ++nt) {
                float p = exp2f((sfr[nt][r] - mn) * LOG2E);
                pf[nt][r] = p;
                rs += p;
            }
            rs += __shfl_xor(rs, 1);
            rs += __shfl_xor(rs, 2);
            rs += __shfl_xor(rs, 4);
            rs += __shfl_xor(rs, 8);
            lsum[r] = lsum[r] * scale + rs;
#pragma unroll
            for (int nt = 0; nt < 4; ++nt) acc[nt][r] *= scale;
        }

        // ---- write P to LDS (bf16, swizzled), re-fragment for PV ----
#pragma unroll
        for (int nt = 0; nt < 4; ++nt) {
            int key = nt * 16 + (lane & 15);
#pragma unroll
            for (int r = 0; r < 4; ++r) {
                int q = (lane >> 4) * 4 + r;
                *(bf16_t*)((char*)&Plds[w][0] + q * 128 +
                           ((key * 2) ^ ((q & 7) << 4))) = (bf16_t)pf[nt][r];
            }
        }
        __syncthreads();

        // ---- O += P V ----
#pragma unroll
        for (int kk = 0; kk < 2; ++kk) {
            int k0 = kk * 32 + (lane >> 4) * 8;
            int q  = lane & 15;
            bf16x8 ap = *(const bf16x8*)((char*)&Plds[w][0] + q * 128 +
                                         ((k0 * 2) ^ ((q & 7) << 4)));
#pragma unroll
            for (int nt = 0; nt < 4; ++nt) {
                int d = nt * 16 + (lane & 15);
                bf16x8 bv = *(const bf16x8*)((char*)Vlds + d * 128 +
                                             ((k0 * 2) ^ ((d & 7) << 4)));
                acc[nt] = __builtin_amdgcn_mfma_f32_16x16x32_bf16(ap, bv, acc[nt], 0, 0, 0);
            }
        }
    }

    // ---- epilogue: normalize and write fp32 ----
    float* ob = out + ((size_t)batch * SS + qtile * 64 + w * 16) * DOUT;
#pragma unroll
    for (int nt = 0; nt < 4; ++nt) {
#pragma unroll
        for (int r = 0; r < 4; ++r) {
            int q = (lane >> 4) * 4 + r;
            int d = nt * 16 + (lane & 15);
            ob[(size_t)q * DOUT + d] = acc[nt][r] / lsum[r];
        }
    }
}

// ---------------------------------------------------------------------------
// Workspace layout (~6.4 MB):
//   [0, 2MB)   Kp bf16 [8][2048][64]
//   [2, 4MB)   Vp bf16
//   [4, 6MB)   Qp bf16 (pre-scaled by 1/8)
//   [6MB, +384KB) fw bf16 [3][65536] fragment-packed weights
// ---------------------------------------------------------------------------
extern "C" void kernel_launch(void* const* d_in, const int* in_sizes, int n_in,
                              void* d_out, int out_size, void* d_ws, size_t ws_size,
                              hipStream_t stream) {
    const float* Xk = (const float*)d_in[0];
    const float* Xv = (const float*)d_in[1];
    const float* Xq = (const float*)d_in[2];
    const float* Kw = (const float*)d_in[3];
    const float* Vw = (const float*)d_in[4];
    const float* Qw = (const float*)d_in[5];

    bf16_t* Kp = (bf16_t*)d_ws;
    bf16_t* Vp = Kp + (size_t)BB * SS * DOUT;
    bf16_t* Qp = Vp + (size_t)BB * SS * DOUT;
    bf16_t* fw = Qp + (size_t)BB * SS * DOUT;

    prep_weights<<<dim3(48), dim3(256), 0, stream>>>(Kw, Vw, Qw, fw);
    proj_kernel<<<dim3(512, 3), dim3(256), 0, stream>>>(Xk, Xv, Xq, fw, Kp, Vp, Qp);
    attn_kernel<<<dim3(32, 8), dim3(256), 0, stream>>>(Kp, Vp, Qp, (float*)d_out);
}

// Round 5
// 113.020 us; speedup vs baseline: 1.0955x; 1.0401x over previous
//
#include <hip/hip_runtime.h>
#include <stdint.h>

// Problem dims (fixed by reference)
#define BB   8
#define SS   2048
#define DIN  1024
#define DOUT 64

typedef __bf16 bf16_t;
typedef __bf16 bf16x4 __attribute__((ext_vector_type(4)));
typedef __bf16 bf16x8 __attribute__((ext_vector_type(8)));
typedef float  f32x4  __attribute__((ext_vector_type(4)));
typedef unsigned int u32x4 __attribute__((ext_vector_type(4)));

#define LOG2E 1.44269504088896f

// ---------------------------------------------------------------------------
// Kernel 0: pre-pack weights (1024x64 fp32) into bf16 MFMA B-fragment order.
// Layout: fw[proj][kk=0..31][nt=0..3][lane=0..63][j=0..7]
//   value = W[k][col],  k = kk*32 + (lane>>4)*8 + j,  col = nt*16 + (lane&15)
// Q weights (proj==2) scaled by 1/sqrt(64) = 0.125 (exact).
// ---------------------------------------------------------------------------
__global__ void prep_weights(const float* __restrict__ Kw,
                             const float* __restrict__ Vw,
                             const float* __restrict__ Qw,
                             bf16_t* __restrict__ fw) {
    int proj = blockIdx.x >> 4;
    int seg  = blockIdx.x & 15;
    const float* W = (proj == 0) ? Kw : (proj == 1) ? Vw : Qw;
    float scale = (proj == 2) ? 0.125f : 1.0f;
    bf16_t* out = fw + proj * 65536;
    int base = seg * 4096;
#pragma unroll
    for (int i = 0; i < 16; ++i) {
        int idx  = base + i * 256 + threadIdx.x;
        int j    = idx & 7;
        int lane = (idx >> 3) & 63;
        int nt   = (idx >> 9) & 3;
        int kk   = idx >> 11;
        int k    = kk * 32 + (lane >> 4) * 8 + j;
        int col  = nt * 16 + (lane & 15);
        out[idx] = (bf16_t)(W[k * DOUT + col] * scale);
    }
}

// ---------------------------------------------------------------------------
// Kernel 1: projection GEMM  [16384,1024](fp32) x [1024,64](bf16) -> bf16
//
// Round-5 structure: CONCURRENCY fix. Rounds 1-4 all had <=32KB of global
// reads in flight per CU (either low waves/CU from 64KB LDS, or ~1 load
// outstanding per wave) -> ~2.5 TB/s latency-bound ceiling.
// Now: 16-row tiles, 32KB LDS -> 4 blocks/CU resident (launch_bounds(256,4),
// 16 waves/CU), and staging issues 8 outstanding f32x4 loads per thread
// before first use (8KB/wave in flight x 16 waves = 128KB/CU).
// Phase 2: wave w computes rows 0-15 x K-quarter [256w,256w+256); B-frags
// from packed fw (L2) with depth-1 register prefetch. Phase 3: LDS reduce.
// ---------------------------------------------------------------------------
__global__ __launch_bounds__(256, 4) void proj_kernel(
    const float* __restrict__ Xk, const float* __restrict__ Xv,
    const float* __restrict__ Xq, const bf16_t* __restrict__ fw,
    bf16_t* __restrict__ outK, bf16_t* __restrict__ outV,
    bf16_t* __restrict__ outQ) {
    __shared__ __align__(128) char Alds[32768];   // 16 rows x 2048B bf16, swizzled

    int tid  = threadIdx.x;
    int lane = tid & 63;
    int w    = tid >> 6;    // 0..3 (K-quarter)

    int proj = blockIdx.y;
    const float* X  = (proj == 0) ? Xk : (proj == 1) ? Xv : Xq;
    bf16_t* out     = (proj == 0) ? outK : (proj == 1) ? outV : outQ;
    const bf16_t* fwp = fw + proj * 65536;

    int row0 = blockIdx.x * 16;

    // ---- Phase 1: stage 16 rows, 2 batches of 8 outstanding loads/thread ----
#pragma unroll
    for (int b = 0; b < 2; ++b) {
        f32x4 v[8];
#pragma unroll
        for (int j = 0; j < 8; ++j)
            v[j] = *(const f32x4*)(X + (size_t)(row0 + b * 8 + j) * DIN + tid * 4);
#pragma unroll
        for (int j = 0; j < 8; ++j) {
            int row = b * 8 + j;
            bf16x4 bv;
            bv[0] = (bf16_t)v[j][0]; bv[1] = (bf16_t)v[j][1];
            bv[2] = (bf16_t)v[j][2]; bv[3] = (bf16_t)v[j][3];
            *(bf16x4*)(Alds + row * 2048 + ((tid * 8) ^ ((row & 7) << 4))) = bv;
        }
    }
    __syncthreads();

    // ---- Phase 2: MFMA over this wave's K-quarter, B depth-1 prefetch ----
    f32x4 acc[4];
#pragma unroll
    for (int nt = 0; nt < 4; ++nt) acc[nt] = (f32x4)(0.0f);

    int arow = lane & 15;
    const bf16_t* bq = fwp + (size_t)(w * 8) * 2048 + lane * 8;  // [kk][nt][512]

    bf16x8 bnow[4];
#pragma unroll
    for (int nt = 0; nt < 4; ++nt) bnow[nt] = *(const bf16x8*)(bq + nt * 512);

#pragma unroll
    for (int kkl = 0; kkl < 8; ++kkl) {
        bf16x8 bnext[4];
        if (kkl < 7) {
#pragma unroll
            for (int nt = 0; nt < 4; ++nt)
                bnext[nt] = *(const bf16x8*)(bq + (kkl + 1) * 2048 + nt * 512);
        }
        int kb = (w * 256 + kkl * 32 + (lane >> 4) * 8) * 2;   // byte offset in row
        bf16x8 a = *(const bf16x8*)(Alds + arow * 2048 + (kb ^ ((arow & 7) << 4)));
#pragma unroll
        for (int nt = 0; nt < 4; ++nt)
            acc[nt] = __builtin_amdgcn_mfma_f32_16x16x32_bf16(a, bnow[nt], acc[nt], 0, 0, 0);
#pragma unroll
        for (int nt = 0; nt < 4; ++nt) bnow[nt] = bnext[nt];
    }

    // ---- Phase 3: reduce K-quarters through LDS (reuse A buffer) ----
    __syncthreads();   // all A-frag reads done
    float* red = (float*)Alds;            // [4][16][64] fp32 = 16 KB
#pragma unroll
    for (int nt = 0; nt < 4; ++nt)
#pragma unroll
        for (int r = 0; r < 4; ++r) {
            int row = (lane >> 4) * 4 + r;
            int col = nt * 16 + (lane & 15);
            red[w * 1024 + row * 64 + col] = acc[nt][r];
        }
    __syncthreads();
    // 256 threads, 4 elements each: col = tid&63, rows (tid>>6)*4 .. +3
#pragma unroll
    for (int i = 0; i < 4; ++i) {
        int row = (tid >> 6) * 4 + i;
        int col = tid & 63;
        float s = red[row * 64 + col] + red[1024 + row * 64 + col] +
                  red[2048 + row * 64 + col] + red[3072 + row * 64 + col];
        out[(size_t)(row0 + row) * DOUT + col] = (bf16_t)s;
    }
}

// ---------------------------------------------------------------------------
// Kernel 2: causal flash attention (round-1 version, unchanged this round).
// Grid: (32 q-tiles, 8 batches). Block: 256 thr = 4 waves x 16 q-rows.
// ---------------------------------------------------------------------------
__global__ __launch_bounds__(256) void attn_kernel(
    const bf16_t* __restrict__ Kp, const bf16_t* __restrict__ Vp,
    const bf16_t* __restrict__ Qp, float* __restrict__ out) {
    __shared__ __align__(16) bf16_t Klds[64 * 64];      // 8 KB
    __shared__ __align__(16) bf16_t Vlds[64 * 64];      // 8 KB (transposed)
    __shared__ __align__(16) bf16_t Plds[4][16 * 64];   // 8 KB

    int tid   = threadIdx.x;
    int lane  = tid & 63;
    int w     = tid >> 6;
    int qtile = blockIdx.x;
    int batch = blockIdx.y;

    const bf16_t* Kb = Kp + (size_t)batch * SS * DOUT;
    const bf16_t* Vb = Vp + (size_t)batch * SS * DOUT;
    const bf16_t* Qb = Qp + (size_t)batch * SS * DOUT;

    bf16x8 aq[2];
    {
        int r = qtile * 64 + w * 16 + (lane & 15);
        const bf16_t* qp = Qb + (size_t)r * DOUT + (lane >> 4) * 8;
        aq[0] = *(const bf16x8*)(qp);
        aq[1] = *(const bf16x8*)(qp + 32);
    }

    float m[4], lsum[4];
    f32x4 acc[4];
#pragma unroll
    for (int r = 0; r < 4; ++r) { m[r] = -1e30f; lsum[r] = 0.0f; }
#pragma unroll
    for (int nt = 0; nt < 4; ++nt) acc[nt] = (f32x4)(0.0f);

    int ntiles = qtile + 1;
    for (int j = 0; j < ntiles; ++j) {
        __syncthreads();
#pragma unroll
        for (int i = 0; i < 2; ++i) {
            int c   = tid + 256 * i;          // 0..511
            int key = c >> 3;
            int d0  = (c & 7) * 8;
            u32x4 v = *(const u32x4*)(Kb + ((size_t)(j * 64 + key)) * DOUT + d0);
            *(u32x4*)((char*)Klds + key * 128 + ((d0 * 2) ^ ((key & 7) << 4))) = v;
        }
#pragma unroll
        for (int i = 0; i < 2; ++i) {
            int c   = tid + 256 * i;
            int key = c >> 3;
            int d0  = (c & 7) * 8;
            bf16x8 v = *(const bf16x8*)(Vb + ((size_t)(j * 64 + key)) * DOUT + d0);
#pragma unroll
            for (int jj = 0; jj < 8; ++jj) {
                int d = d0 + jj;
                *(bf16_t*)((char*)Vlds + d * 128 + ((key * 2) ^ ((d & 7) << 4))) = v[jj];
            }
        }
        __syncthreads();

        f32x4 sfr[4];
#pragma unroll
        for (int nt = 0; nt < 4; ++nt) sfr[nt] = (f32x4)(0.0f);
#pragma unroll
        for (int kk = 0; kk < 2; ++kk) {
            int d0 = kk * 32 + (lane >> 4) * 8;
#pragma unroll
            for (int nt = 0; nt < 4; ++nt) {
                int key = nt * 16 + (lane & 15);
                bf16x8 bk = *(const bf16x8*)((char*)Klds + key * 128 +
                                             ((d0 * 2) ^ ((key & 7) << 4)));
                sfr[nt] = __builtin_amdgcn_mfma_f32_16x16x32_bf16(aq[kk], bk, sfr[nt], 0, 0, 0);
            }
        }

        if (j == qtile) {
#pragma unroll
            for (int nt = 0; nt < 4; ++nt) {
                int key = nt * 16 + (lane & 15);
#pragma unroll
                for (int r = 0; r < 4; ++r) {
                    int q = w * 16 + (lane >> 4) * 4 + r;
                    if (key > q) sfr[nt][r] = -1e30f;
                }
            }
        }

        float pf[4][4];
#pragma unroll
        for (int r = 0; r < 4; ++r) {
            float mx = fmaxf(fmaxf(sfr[0][r], sfr[1][r]), fmaxf(sfr[2][r], sfr[3][r]));
            mx = fmaxf(mx, __shfl_xor(mx, 1));
            mx = fmaxf(mx, __shfl_xor(mx, 2));
            mx = fmaxf(mx, __shfl_xor(mx, 4));
            mx = fmaxf(mx, __shfl_xor(mx, 8));
            float mn = fmaxf(m[r], mx);
            float scale = exp2f((m[r] - mn) * LOG2E);
            m[r] = mn;
            float rs = 0.0f;
#pragma unroll
            for (int nt = 0; nt < 4; ++nt) {
                float p = exp2f((sfr[nt][r] - mn) * LOG2E);
                pf[nt][r] = p;
                rs += p;
            }
            rs += __shfl_xor(rs, 1);
            rs += __shfl_xor(rs, 2);
            rs += __shfl_xor(rs, 4);
            rs += __shfl_xor(rs, 8);
            lsum[r] = lsum[r] * scale + rs;
#pragma unroll
            for (int nt = 0; nt < 4; ++nt) acc[nt][r] *= scale;
        }

#pragma unroll
        for (int nt = 0; nt < 4; ++nt) {
            int key = nt * 16 + (lane & 15);
#pragma unroll
            for (int r = 0; r < 4; ++r) {
                int q = (lane >> 4) * 4 + r;
                *(bf16_t*)((char*)&Plds[w][0] + q * 128 +
                           ((key * 2) ^ ((q & 7) << 4))) = (bf16_t)pf[nt][r];
            }
        }
        __syncthreads();

#pragma unroll
        for (int kk = 0; kk < 2; ++kk) {
            int k0 = kk * 32 + (lane >> 4) * 8;
            int q  = lane & 15;
            bf16x8 ap = *(const bf16x8*)((char*)&Plds[w][0] + q * 128 +
                                         ((k0 * 2) ^ ((q & 7) << 4)));
#pragma unroll
            for (int nt = 0; nt < 4; ++nt) {
                int d = nt * 16 + (lane & 15);
                bf16x8 bv = *(const bf16x8*)((char*)Vlds + d * 128 +
                                             ((k0 * 2) ^ ((d & 7) << 4)));
                acc[nt] = __builtin_amdgcn_mfma_f32_16x16x32_bf16(ap, bv, acc[nt], 0, 0, 0);
            }
        }
    }

    float* ob = out + ((size_t)batch * SS + qtile * 64 + w * 16) * DOUT;
#pragma unroll
    for (int nt = 0; nt < 4; ++nt) {
#pragma unroll
        for (int r = 0; r < 4; ++r) {
            int q = (lane >> 4) * 4 + r;
            int d = nt * 16 + (lane & 15);
            ob[(size_t)q * DOUT + d] = acc[nt][r] / lsum[r];
        }
    }
}

// ---------------------------------------------------------------------------
// Workspace layout (~6.4 MB):
//   [0, 2MB)   Kp bf16 [8][2048][64]
//   [2, 4MB)   Vp bf16
//   [4, 6MB)   Qp bf16 (pre-scaled by 1/8)
//   [6MB, +384KB) fw bf16 [3][65536] fragment-packed weights
// ---------------------------------------------------------------------------
extern "C" void kernel_launch(void* const* d_in, const int* in_sizes, int n_in,
                              void* d_out, int out_size, void* d_ws, size_t ws_size,
                              hipStream_t stream) {
    const float* Xk = (const float*)d_in[0];
    const float* Xv = (const float*)d_in[1];
    const float* Xq = (const float*)d_in[2];
    const float* Kw = (const float*)d_in[3];
    const float* Vw = (const float*)d_in[4];
    const float* Qw = (const float*)d_in[5];

    bf16_t* Kp = (bf16_t*)d_ws;
    bf16_t* Vp = Kp + (size_t)BB * SS * DOUT;
    bf16_t* Qp = Vp + (size_t)BB * SS * DOUT;
    bf16_t* fw = Qp + (size_t)BB * SS * DOUT;

    prep_weights<<<dim3(48), dim3(256), 0, stream>>>(Kw, Vw, Qw, fw);
    proj_kernel<<<dim3(1024, 3), dim3(256), 0, stream>>>(Xk, Xv, Xq, fw, Kp, Vp, Qp);
    attn_kernel<<<dim3(32, 8), dim3(256), 0, stream>>>(Kp, Vp, Qp, (float*)d_out);
}

// Round 6
// 109.682 us; speedup vs baseline: 1.1288x; 1.0304x over previous
//
#include <hip/hip_runtime.h>
#include <stdint.h>

// Problem dims (fixed by reference)
#define BB   8
#define SS   2048
#define DIN  1024
#define DOUT 64

typedef __bf16 bf16_t;
typedef __bf16 bf16x4 __attribute__((ext_vector_type(4)));
typedef __bf16 bf16x8 __attribute__((ext_vector_type(8)));
typedef float  f32x4  __attribute__((ext_vector_type(4)));
typedef unsigned int u32x4 __attribute__((ext_vector_type(4)));

#define LOG2E 1.44269504088896f

// Async global->LDS, 16B per lane, zero VGPR cost. LDS dest must be
// wave-uniform base (+ lane*16 implicit); global src is per-lane.
__device__ __forceinline__ void load_lds16(const void* g, void* l) {
    __builtin_amdgcn_global_load_lds(
        (const __attribute__((address_space(1))) void*)g,
        (__attribute__((address_space(3))) void*)l, 16, 0, 0);
}

// ---------------------------------------------------------------------------
// Kernel 0: pre-pack weights (1024x64 fp32) into bf16 MFMA B-fragment order.
// Layout: fw[proj][kk=0..31][nt=0..3][lane=0..63][j=0..7]
//   value = W[k][col],  k = kk*32 + (lane>>4)*8 + j,  col = nt*16 + (lane&15)
// Q weights (proj==2) scaled by 1/sqrt(64) = 0.125 (exact).
// ---------------------------------------------------------------------------
__global__ void prep_weights(const float* __restrict__ Kw,
                             const float* __restrict__ Vw,
                             const float* __restrict__ Qw,
                             bf16_t* __restrict__ fw) {
    int proj = blockIdx.x >> 4;
    int seg  = blockIdx.x & 15;
    const float* W = (proj == 0) ? Kw : (proj == 1) ? Vw : Qw;
    float scale = (proj == 2) ? 0.125f : 1.0f;
    bf16_t* out = fw + proj * 65536;
    int base = seg * 4096;
#pragma unroll
    for (int i = 0; i < 16; ++i) {
        int idx  = base + i * 256 + threadIdx.x;
        int j    = idx & 7;
        int lane = (idx >> 3) & 63;
        int nt   = (idx >> 9) & 3;
        int kk   = idx >> 11;
        int k    = kk * 32 + (lane >> 4) * 8 + j;
        int col  = nt * 16 + (lane & 15);
        out[idx] = (bf16_t)(W[k * DOUT + col] * scale);
    }
}

// ---------------------------------------------------------------------------
// Kernel 1: projection GEMM  [16384,1024](fp32) x [1024,64](bf16) -> bf16
//
// Round-6: async staging via global_load_lds (zero-VGPR, regalloc-immune —
// rounds 2/3/5's register pipelines were all serialized by the allocator,
// VGPR_Count 32/88/44 prove it). m97-style single-buffer loop:
//   stage A(2 calls) + B(2 calls) -> barrier(vmcnt drain) -> compute -> barrier
// Cross-block overlap (6 blocks/CU, 16KB LDS) hides the drain.
// A LDS [32 rows][64 fp32], 16B-block-swizzled: physical blk = logical ^ (row&15),
// realized by pre-swizzling the GLOBAL source column (gload_lds writes linear).
// B LDS = linear 8KB slice of fragment-packed fw (per-lane contiguous reads).
// Each wave owns 2 output tiles (rowtile = w&1, nt = (w>>1)*2 + {0,1}) over
// the FULL K -> no cross-wave reduction.
// ---------------------------------------------------------------------------
__global__ __launch_bounds__(256) void proj_kernel(
    const float* __restrict__ Xk, const float* __restrict__ Xv,
    const float* __restrict__ Xq, const bf16_t* __restrict__ fw,
    bf16_t* __restrict__ outK, bf16_t* __restrict__ outV,
    bf16_t* __restrict__ outQ) {
    __shared__ __align__(128) char Al[8192];   // [32 rows][256B], swizzled
    __shared__ __align__(128) char Bl[8192];   // [s(2)][nt(4)][64 lanes][16B]

    int tid  = threadIdx.x;
    int lane = tid & 63;
    int w    = tid >> 6;    // 0..3

    int proj = blockIdx.y;
    const float* X  = (proj == 0) ? Xk : (proj == 1) ? Xv : Xq;
    bf16_t* out     = (proj == 0) ? outK : (proj == 1) ? outV : outQ;
    const bf16_t* fwp = fw + proj * 65536;

    int row0 = blockIdx.x * 32;

    // staging source: thread t covers (row0 + i*16 + (t>>4), 16B-block (t&15)^(t>>4))
    const float* ga = X + (size_t)(row0 + (tid >> 4)) * DIN + ((tid & 15) ^ (tid >> 4)) * 4;
    char* alds0 = Al + (w << 10);
    char* alds1 = Al + 4096 + (w << 10);
    char* blds0 = Bl + (w << 10);
    char* blds1 = Bl + 4096 + (w << 10);

    f32x4 acc0 = (f32x4)(0.0f), acc1 = (f32x4)(0.0f);
    int r   = (w & 1) * 16 + (lane & 15);     // tile-local row for A-frags
    int nt0 = (w >> 1) * 2;

    for (int kt = 0; kt < 16; ++kt) {
        // ---- async stage: A (8KB) + B (8KB), 4 insts/thread, no VGPRs ----
        load_lds16(ga + kt * 64,               alds0);
        load_lds16(ga + 16 * DIN + kt * 64,    alds1);
        load_lds16(fwp + kt * 4096 + tid * 8,        blds0);
        load_lds16(fwp + kt * 4096 + 2048 + tid * 8, blds1);
        __syncthreads();   // compiler drains vmcnt(0) here

#pragma unroll
        for (int s = 0; s < 2; ++s) {
            int b0 = s * 8 + (lane >> 4) * 2;        // logical 16B blocks
            f32x4 lo = *(const f32x4*)(Al + r * 256 + (((b0    ) ^ (lane & 15)) << 4));
            f32x4 hi = *(const f32x4*)(Al + r * 256 + (((b0 + 1) ^ (lane & 15)) << 4));
            bf16x8 af;
            af[0] = (bf16_t)lo[0]; af[1] = (bf16_t)lo[1];
            af[2] = (bf16_t)lo[2]; af[3] = (bf16_t)lo[3];
            af[4] = (bf16_t)hi[0]; af[5] = (bf16_t)hi[1];
            af[6] = (bf16_t)hi[2]; af[7] = (bf16_t)hi[3];
            bf16x8 bf0 = *(const bf16x8*)(Bl + s * 4096 + nt0 * 1024 + lane * 16);
            bf16x8 bf1 = *(const bf16x8*)(Bl + s * 4096 + (nt0 + 1) * 1024 + lane * 16);
            acc0 = __builtin_amdgcn_mfma_f32_16x16x32_bf16(af, bf0, acc0, 0, 0, 0);
            acc1 = __builtin_amdgcn_mfma_f32_16x16x32_bf16(af, bf1, acc1, 0, 0, 0);
        }
        __syncthreads();   // protect LDS for next k-step's stage
    }

    // ---- store: C/D layout col = lane&15, row = (lane>>4)*4 + j ----
#pragma unroll
    for (int j = 0; j < 4; ++j) {
        int orow = row0 + (w & 1) * 16 + (lane >> 4) * 4 + j;
        out[(size_t)orow * DOUT + nt0 * 16 + (lane & 15)]       = (bf16_t)acc0[j];
        out[(size_t)orow * DOUT + (nt0 + 1) * 16 + (lane & 15)] = (bf16_t)acc1[j];
    }
}

// ---------------------------------------------------------------------------
// Kernel 2: causal flash attention (round-1 version, unchanged this round).
// Grid: (32 q-tiles, 8 batches). Block: 256 thr = 4 waves x 16 q-rows.
// ---------------------------------------------------------------------------
__global__ __launch_bounds__(256) void attn_kernel(
    const bf16_t* __restrict__ Kp, const bf16_t* __restrict__ Vp,
    const bf16_t* __restrict__ Qp, float* __restrict__ out) {
    __shared__ __align__(16) bf16_t Klds[64 * 64];      // 8 KB
    __shared__ __align__(16) bf16_t Vlds[64 * 64];      // 8 KB (transposed)
    __shared__ __align__(16) bf16_t Plds[4][16 * 64];   // 8 KB

    int tid   = threadIdx.x;
    int lane  = tid & 63;
    int w     = tid >> 6;
    int qtile = blockIdx.x;
    int batch = blockIdx.y;

    const bf16_t* Kb = Kp + (size_t)batch * SS * DOUT;
    const bf16_t* Vb = Vp + (size_t)batch * SS * DOUT;
    const bf16_t* Qb = Qp + (size_t)batch * SS * DOUT;

    bf16x8 aq[2];
    {
        int r = qtile * 64 + w * 16 + (lane & 15);
        const bf16_t* qp = Qb + (size_t)r * DOUT + (lane >> 4) * 8;
        aq[0] = *(const bf16x8*)(qp);
        aq[1] = *(const bf16x8*)(qp + 32);
    }

    float m[4], lsum[4];
    f32x4 acc[4];
#pragma unroll
    for (int r = 0; r < 4; ++r) { m[r] = -1e30f; lsum[r] = 0.0f; }
#pragma unroll
    for (int nt = 0; nt < 4; ++nt) acc[nt] = (f32x4)(0.0f);

    int ntiles = qtile + 1;
    for (int j = 0; j < ntiles; ++j) {
        __syncthreads();
#pragma unroll
        for (int i = 0; i < 2; ++i) {
            int c   = tid + 256 * i;          // 0..511
            int key = c >> 3;
            int d0  = (c & 7) * 8;
            u32x4 v = *(const u32x4*)(Kb + ((size_t)(j * 64 + key)) * DOUT + d0);
            *(u32x4*)((char*)Klds + key * 128 + ((d0 * 2) ^ ((key & 7) << 4))) = v;
        }
#pragma unroll
        for (int i = 0; i < 2; ++i) {
            int c   = tid + 256 * i;
            int key = c >> 3;
            int d0  = (c & 7) * 8;
            bf16x8 v = *(const bf16x8*)(Vb + ((size_t)(j * 64 + key)) * DOUT + d0);
#pragma unroll
            for (int jj = 0; jj < 8; ++jj) {
                int d = d0 + jj;
                *(bf16_t*)((char*)Vlds + d * 128 + ((key * 2) ^ ((d & 7) << 4))) = v[jj];
            }
        }
        __syncthreads();

        f32x4 sfr[4];
#pragma unroll
        for (int nt = 0; nt < 4; ++nt) sfr[nt] = (f32x4)(0.0f);
#pragma unroll
        for (int kk = 0; kk < 2; ++kk) {
            int d0 = kk * 32 + (lane >> 4) * 8;
#pragma unroll
            for (int nt = 0; nt < 4; ++nt) {
                int key = nt * 16 + (lane & 15);
                bf16x8 bk = *(const bf16x8*)((char*)Klds + key * 128 +
                                             ((d0 * 2) ^ ((key & 7) << 4)));
                sfr[nt] = __builtin_amdgcn_mfma_f32_16x16x32_bf16(aq[kk], bk, sfr[nt], 0, 0, 0);
            }
        }

        if (j == qtile) {
#pragma unroll
            for (int nt = 0; nt < 4; ++nt) {
                int key = nt * 16 + (lane & 15);
#pragma unroll
                for (int r = 0; r < 4; ++r) {
                    int q = w * 16 + (lane >> 4) * 4 + r;
                    if (key > q) sfr[nt][r] = -1e30f;
                }
            }
        }

        float pf[4][4];
#pragma unroll
        for (int r = 0; r < 4; ++r) {
            float mx = fmaxf(fmaxf(sfr[0][r], sfr[1][r]), fmaxf(sfr[2][r], sfr[3][r]));
            mx = fmaxf(mx, __shfl_xor(mx, 1));
            mx = fmaxf(mx, __shfl_xor(mx, 2));
            mx = fmaxf(mx, __shfl_xor(mx, 4));
            mx = fmaxf(mx, __shfl_xor(mx, 8));
            float mn = fmaxf(m[r], mx);
            float scale = exp2f((m[r] - mn) * LOG2E);
            m[r] = mn;
            float rs = 0.0f;
#pragma unroll
            for (int nt = 0; nt < 4; ++nt) {
                float p = exp2f((sfr[nt][r] - mn) * LOG2E);
                pf[nt][r] = p;
                rs += p;
            }
            rs += __shfl_xor(rs, 1);
            rs += __shfl_xor(rs, 2);
            rs += __shfl_xor(rs, 4);
            rs += __shfl_xor(rs, 8);
            lsum[r] = lsum[r] * scale + rs;
#pragma unroll
            for (int nt = 0; nt < 4; ++nt) acc[nt][r] *= scale;
        }

#pragma unroll
        for (int nt = 0; nt < 4; ++nt) {
            int key = nt * 16 + (lane & 15);
#pragma unroll
            for (int r = 0; r < 4; ++r) {
                int q = (lane >> 4) * 4 + r;
                *(bf16_t*)((char*)&Plds[w][0] + q * 128 +
                           ((key * 2) ^ ((q & 7) << 4))) = (bf16_t)pf[nt][r];
            }
        }
        __syncthreads();

#pragma unroll
        for (int kk = 0; kk < 2; ++kk) {
            int k0 = kk * 32 + (lane >> 4) * 8;
            int q  = lane & 15;
            bf16x8 ap = *(const bf16x8*)((char*)&Plds[w][0] + q * 128 +
                                         ((k0 * 2) ^ ((q & 7) << 4)));
#pragma unroll
            for (int nt = 0; nt < 4; ++nt) {
                int d = nt * 16 + (lane & 15);
                bf16x8 bv = *(const bf16x8*)((char*)Vlds + d * 128 +
                                             ((k0 * 2) ^ ((d & 7) << 4)));
                acc[nt] = __builtin_amdgcn_mfma_f32_16x16x32_bf16(ap, bv, acc[nt], 0, 0, 0);
            }
        }
    }

    float* ob = out + ((size_t)batch * SS + qtile * 64 + w * 16) * DOUT;
#pragma unroll
    for (int nt = 0; nt < 4; ++nt) {
#pragma unroll
        for (int r = 0; r < 4; ++r) {
            int q = (lane >> 4) * 4 + r;
            int d = nt * 16 + (lane & 15);
            ob[(size_t)q * DOUT + d] = acc[nt][r] / lsum[r];
        }
    }
}

// ---------------------------------------------------------------------------
// Workspace layout (~6.4 MB):
//   [0, 2MB)   Kp bf16 [8][2048][64]
//   [2, 4MB)   Vp bf16
//   [4, 6MB)   Qp bf16 (pre-scaled by 1/8)
//   [6MB, +384KB) fw bf16 [3][65536] fragment-packed weights
// ---------------------------------------------------------------------------
extern "C" void kernel_launch(void* const* d_in, const int* in_sizes, int n_in,
                              void* d_out, int out_size, void* d_ws, size_t ws_size,
                              hipStream_t stream) {
    const float* Xk = (const float*)d_in[0];
    const float* Xv = (const float*)d_in[1];
    const float* Xq = (const float*)d_in[2];
    const float* Kw = (const float*)d_in[3];
    const float* Vw = (const float*)d_in[4];
    const float* Qw = (const float*)d_in[5];

    bf16_t* Kp = (bf16_t*)d_ws;
    bf16_t* Vp = Kp + (size_t)BB * SS * DOUT;
    bf16_t* Qp = Vp + (size_t)BB * SS * DOUT;
    bf16_t* fw = Qp + (size_t)BB * SS * DOUT;

    prep_weights<<<dim3(48), dim3(256), 0, stream>>>(Kw, Vw, Qw, fw);
    proj_kernel<<<dim3(512, 3), dim3(256), 0, stream>>>(Xk, Xv, Xq, fw, Kp, Vp, Qp);
    attn_kernel<<<dim3(32, 8), dim3(256), 0, stream>>>(Kp, Vp, Qp, (float*)d_out);
}